// Round 17
// baseline (373.768 us; speedup 1.0000x reference)
//
#include <hip/hip_runtime.h>
#include <hip/hip_bf16.h>

typedef short short8 __attribute__((ext_vector_type(8)));
typedef unsigned short u16x8 __attribute__((ext_vector_type(8)));
typedef float f32x4 __attribute__((ext_vector_type(4)));

#define AS1 __attribute__((address_space(1)))
#define AS3 __attribute__((address_space(3)))

__device__ __forceinline__ void gload16(const void* g, void* l) {
  __builtin_amdgcn_global_load_lds((AS1 void*)g, (AS3 void*)l, 16, 0, 0);
}

__device__ __forceinline__ unsigned short f2bf(float f) {
  unsigned u = __float_as_uint(f);
  u = (u + 0x7FFF + ((u >> 16) & 1)) >> 16;  // RNE
  return (unsigned short)u;
}
__device__ __forceinline__ float bf2f(unsigned short u) {
  return __uint_as_float(((unsigned)u) << 16);
}

// ---------------- prep: x f32->bf16 (vectorized) + W1/W2 transpose-convert ----------------
__global__ void prep_kernel(const float4* __restrict__ x4, ushort4* __restrict__ xb4, int n4,
                            const float* __restrict__ W1, unsigned short* __restrict__ W1t,
                            const float* __restrict__ W2, unsigned short* __restrict__ W2t) {
  const int nthr = gridDim.x * 256;
  for (int i = blockIdx.x * 256 + threadIdx.x; i < n4; i += nthr) {
    float4 v = x4[i];
    ushort4 o;
    o.x = f2bf(v.x); o.y = f2bf(v.y); o.z = f2bf(v.z); o.w = f2bf(v.w);
    xb4[i] = o;
  }
  for (int idx = blockIdx.x * 256 + threadIdx.x; idx < 512 * 512; idx += nthr) {
    const int k = idx >> 9, n = idx & 511;
    W1t[n * 512 + k] = f2bf(W1[idx]);
    W2t[n * 512 + k] = f2bf(W2[idx]);
  }
}

// ---------------- edge dtype detector (wave-parallel) ----------------
__global__ void detect64_kernel(const int* __restrict__ ei32, int* __restrict__ flag) {
  const int lane = threadIdx.x;
  const int v = ei32[2 * lane + 1];
  const unsigned long long m = __ballot(v != 0);
  if (lane == 0) *flag = (m == 0ull) ? 1 : 0;
}

// ---------------- CSR build (per-node lists quartile-sorted by source) ----------------
__global__ void count_kernel(const int* __restrict__ ei32, const int* __restrict__ flag,
                             int* __restrict__ cnt4, int E, int qdiv) {
  int e = blockIdx.x * 256 + threadIdx.x;
  if (e >= E) return;
  const int is64 = *flag;
  const int r = is64 ? ei32[2 * e] : ei32[e];
  const int c = is64 ? ei32[2 * E + 2 * e] : ei32[E + e];
  int q = r / qdiv; q = q > 3 ? 3 : q;
  atomicAdd(&cnt4[c * 4 + q], 1);
}

__global__ void __launch_bounds__(1024) scan_bsum_kernel(const int* __restrict__ cnt,
                                                         int* __restrict__ bsum, int n) {
  __shared__ int ws[16];
  const int tid = threadIdx.x, lane = tid & 63, wid = tid >> 6;
  const int i = blockIdx.x * 1024 + tid;
  int x = (i < n) ? cnt[i] : 0;
#pragma unroll
  for (int d = 1; d < 64; d <<= 1) x += __shfl_xor(x, d, 64);
  if (lane == 0) ws[wid] = x;
  __syncthreads();
  if (tid == 0) {
    int s = 0;
#pragma unroll
    for (int w = 0; w < 16; ++w) s += ws[w];
    bsum[blockIdx.x] = s;
  }
}

__global__ void __launch_bounds__(1024) scan_boff_kernel(int* __restrict__ bsum,
                                                         int* __restrict__ total, int B) {
  __shared__ int ws[16];
  const int tid = threadIdx.x, lane = tid & 63, wid = tid >> 6;
  const int v = (tid < B) ? bsum[tid] : 0;
  int x = v;
#pragma unroll
  for (int d = 1; d < 64; d <<= 1) {
    int y = __shfl_up(x, d, 64);
    if (lane >= d) x += y;
  }
  if (lane == 63) ws[wid] = x;
  __syncthreads();
  if (tid < 16) {
    int wv = ws[tid];
    int wx = wv;
#pragma unroll
    for (int d = 1; d < 16; d <<= 1) {
      int y = __shfl_up(wx, d, 64);
      if (tid >= d) wx += y;
    }
    ws[tid] = wx - wv;
  }
  __syncthreads();
  const int excl = ws[wid] + (x - v);
  if (tid < B) bsum[tid] = excl;
  if (tid == B - 1) *total = excl + v;
}

__global__ void __launch_bounds__(1024) scan_fill_kernel(const int* __restrict__ cnt,
    const int* __restrict__ boff, int* __restrict__ ptr, int* __restrict__ cur,
    float* __restrict__ dis, int n) {
  __shared__ int ws[16];
  const int tid = threadIdx.x, lane = tid & 63, wid = tid >> 6;
  const int j = blockIdx.x * 1024 + tid;
  const int v = (j < n) ? cnt[j] : 0;
  int x = v;
#pragma unroll
  for (int d = 1; d < 64; d <<= 1) {
    int y = __shfl_up(x, d, 64);
    if (lane >= d) x += y;
  }
  if (lane == 63) ws[wid] = x;
  __syncthreads();
  if (tid < 16) {
    int wv = ws[tid];
    int wx = wv;
#pragma unroll
    for (int d = 1; d < 16; d <<= 1) {
      int y = __shfl_up(wx, d, 64);
      if (tid >= d) wx += y;
    }
    ws[tid] = wx - wv;
  }
  __syncthreads();
  const int v1 = __shfl_down(v, 1, 64);
  const int v2 = __shfl_down(v, 2, 64);
  const int v3 = __shfl_down(v, 3, 64);
  if (j < n) {
    const int excl = boff[blockIdx.x] + ws[wid] + (x - v);
    ptr[j] = excl;
    cur[j] = excl;
    if ((j & 3) == 0) dis[j >> 2] = rsqrtf((float)(v + v1 + v2 + v3 + 1));  // +1 self-loop
  }
}

__global__ void fill_kernel(const int* __restrict__ ei32, const int* __restrict__ flag,
                            int* __restrict__ cur4, int* __restrict__ eidx, int E, int qdiv) {
  int e = blockIdx.x * 256 + threadIdx.x;
  if (e >= E) return;
  const int is64 = *flag;
  const int r = is64 ? ei32[2 * e] : ei32[e];
  const int c = is64 ? ei32[2 * E + 2 * e] : ei32[E + e];
  int q = r / qdiv; q = q > 3 ? 3 : q;
  const int pos = atomicAdd(&cur4[c * 4 + q], 1);
  eidx[pos] = r;
}

// ---------------- bf16 MFMA GEMM: C = (A @ Bt^T) * dscale[row] (R12 form) ----------------
// 128x128 tile, BK=64, single-buffered (32KB LDS, 3+ blocks/CU), XOR slot-swizzle,
// XCD-chunk swizzle. BA: A column-blocked [8][M][64]; BC: C written column-blocked.
template <bool BA, bool BC>
__global__ void __launch_bounds__(256, 3) gemm_kernel(const unsigned short* __restrict__ A,
                                                      const unsigned short* __restrict__ Bt,
                                                      const float* __restrict__ dscale,
                                                      unsigned short* __restrict__ C, int M) {
  __shared__ alignas(128) unsigned short As[8192];
  __shared__ alignas(128) unsigned short Bs[8192];
  const int tid = threadIdx.x;
  const int wave = tid >> 6, lane = tid & 63;
  const int wm = wave >> 1, wn = wave & 1;

  const int nbm = (M + 127) >> 7;
  const int nwg = nbm * 4;
  const int orig = blockIdx.x;
  const int xcd = orig & 7;
  const int q8 = nwg >> 3, r8 = nwg & 7;
  const int wg = (xcd < r8 ? xcd * (q8 + 1) : r8 * (q8 + 1) + (xcd - r8) * q8) + (orig >> 3);
  const int bn = wg & 3;
  const int bm = wg >> 2;

  const int lr = lane >> 3, ls = lane & 7;
  const int fr = lane & 15, ks = lane >> 4;

  f32x4 acc[4][4] = {};

#define STAGE(KO)                                                                          \
  {                                                                                        \
    _Pragma("unroll") for (int i = 0; i < 4; ++i) {                                        \
      int ra = bm * 128 + i * 32 + wave * 8 + lr;                                          \
      ra = ra < M ? ra : M - 1;                                                            \
      const size_t aoff = BA ? ((size_t)(KO)*M + (size_t)ra * 64 + ((ls ^ (lr & 7)) << 3)) \
                             : ((size_t)ra * 512 + (KO) + ((ls ^ (lr & 7)) << 3));         \
      gload16(A + aoff, &As[(i * 32 + wave * 8) * 64]);                                    \
      const int rb = bn * 128 + i * 32 + wave * 8 + lr;                                    \
      gload16(Bt + (size_t)rb * 512 + (KO) + ((ls ^ (lr & 7)) << 3),                       \
              &Bs[(i * 32 + wave * 8) * 64]);                                              \
    }                                                                                      \
  }

  for (int kt = 0; kt < 8; ++kt) {
    if (kt) __syncthreads();
    STAGE(kt * 64)
    __syncthreads();

#pragma unroll
    for (int kk = 0; kk < 2; ++kk) {
      short8 af[4], bfg[4];
#pragma unroll
      for (int m = 0; m < 4; ++m) {
        const int tr = wm * 64 + m * 16 + fr;
        af[m] = *(const short8*)&As[tr * 64 + ((ks * 8 + kk * 32) ^ ((tr & 7) << 3))];
      }
#pragma unroll
      for (int n = 0; n < 4; ++n) {
        const int tb = wn * 64 + n * 16 + fr;
        bfg[n] = *(const short8*)&Bs[tb * 64 + ((ks * 8 + kk * 32) ^ ((tb & 7) << 3))];
      }
#pragma unroll
      for (int m = 0; m < 4; ++m)
#pragma unroll
        for (int n = 0; n < 4; ++n)
          acc[m][n] = __builtin_amdgcn_mfma_f32_16x16x32_bf16(af[m], bfg[n], acc[m][n], 0, 0, 0);
    }
  }
#undef STAGE

  const int rbase = bm * 128 + wm * 64 + (lane >> 4) * 4;
  const int cbase = bn * 128 + wn * 64 + (lane & 15);
  const size_t hseg = (size_t)M * 64;
#pragma unroll
  for (int m = 0; m < 4; ++m)
#pragma unroll
    for (int j = 0; j < 4; ++j) {
      const int r = rbase + m * 16 + j;
      if (r < M) {
        const float ds = dscale[r];
#pragma unroll
        for (int n = 0; n < 4; ++n) {
          const unsigned short val = f2bf(acc[m][n][j] * ds);
          if (BC) {
            const int col = cbase + n * 16;
            C[(size_t)(col >> 6) * hseg + (size_t)r * 64 + (col & 63)] = val;
          } else {
            C[(size_t)r * 512 + cbase + n * 16] = val;
          }
        }
      }
    }
}

// ---------------- aggregation: XCD-pinned slices, 2-deep quad-rotated gathers -----------
// h layout: [8 slices][M][64]; 8-lane group owns one node. Quad i+1's gathers are issued
// BEFORE quad i's FMA consumes its data -> one quad of latency exposed per node, not per quad.
template <bool FINAL>
__global__ void __launch_bounds__(256) agg_kernel(const unsigned short* __restrict__ h,
    const int* __restrict__ eidx, const int* __restrict__ ptr4, const float* __restrict__ dis,
    const float* __restrict__ bias, void* __restrict__ outv, int n) {
  const int tid = threadIdx.x;
  const int lane = tid & 63;
  const int slice = blockIdx.x & 7;
  const int g = lane >> 3;
  const int c = lane & 7;
  const int node = (int)(blockIdx.x >> 3) * 32 + (tid >> 6) * 8 + g;
  if (node >= n) return;

  const unsigned short* hs = h + (size_t)slice * ((size_t)n * 64);
  const int coff = c * 8;

  const int start = ptr4[node * 4], end = ptr4[node * 4 + 4];
  float acc[8] = {0, 0, 0, 0, 0, 0, 0, 0};

#define GATH(S) (*(const u16x8*)(hs + (size_t)(unsigned)(S) * 64 + coff))
#define FMA1(V)                                        \
  _Pragma("unroll") for (int j = 0; j < 8; ++j) acc[j] += bf2f((V)[j]);
#define FMA4(A0, A1, A2, A3)                                                   \
  _Pragma("unroll") for (int j = 0; j < 8; ++j)                                \
      acc[j] += bf2f((A0)[j]) + bf2f((A1)[j]) + bf2f((A2)[j]) + bf2f((A3)[j]);

  int e = start;
  const int alim = min(end, (start + 3) & ~3);  // align to 4 for int4 eidx loads
  for (; e < alim; ++e) {
    const u16x8 v = GATH(eidx[e]);
    FMA1(v)
  }
  const int nq = (end - e) >> 2;
  if (nq > 0) {
    int4 si = *(const int4*)&eidx[e];
    u16x8 v0 = GATH(si.x), v1 = GATH(si.y), v2 = GATH(si.z), v3 = GATH(si.w);
    for (int q = 1; q < nq; ++q) {
      const int4 sn = *(const int4*)&eidx[e + 4 * q];
      const u16x8 w0 = GATH(sn.x), w1 = GATH(sn.y), w2 = GATH(sn.z), w3 = GATH(sn.w);
      FMA4(v0, v1, v2, v3)       // consumes quad q-1 while quad q's gathers fly
      v0 = w0; v1 = w1; v2 = w2; v3 = w3;
    }
    FMA4(v0, v1, v2, v3)
    e += nq * 4;
  }
  for (; e < end; ++e) {
    const u16x8 v = GATH(eidx[e]);
    FMA1(v)
  }
  {  // self loop
    const u16x8 v = GATH(node);
    FMA1(v)
  }
#undef FMA4
#undef FMA1
#undef GATH

  const float di = dis[node];
  const int fcol = slice * 64 + coff;
  float b[8];
  *(float4*)&b[0] = *(const float4*)(bias + fcol);
  *(float4*)&b[4] = *(const float4*)(bias + fcol + 4);

  if (FINAL) {
    float* out = (float*)outv;
    float4 o0, o1;
    o0.x = acc[0] * di + b[0]; o0.y = acc[1] * di + b[1];
    o0.z = acc[2] * di + b[2]; o0.w = acc[3] * di + b[3];
    o1.x = acc[4] * di + b[4]; o1.y = acc[5] * di + b[5];
    o1.z = acc[6] * di + b[6]; o1.w = acc[7] * di + b[7];
    *(float4*)(out + (size_t)node * 512 + fcol) = o0;
    *(float4*)(out + (size_t)node * 512 + fcol + 4) = o1;
  } else {  // column-blocked bf16 (feeds GEMM2 blocked-A)
    unsigned short* out = (unsigned short*)outv;
    u16x8 o;
#pragma unroll
    for (int j = 0; j < 8; ++j) {
      const float t = acc[j] * di + b[j];
      o[j] = f2bf(t > 0.0f ? t : 0.0f);
    }
    *(u16x8*)(out + (size_t)slice * ((size_t)n * 64) + (size_t)node * 64 + coff) = o;
  }
}

// ---------------- launch ----------------
extern "C" void kernel_launch(void* const* d_in, const int* in_sizes, int n_in,
                              void* d_out, int out_size, void* d_ws, size_t ws_size,
                              hipStream_t stream) {
  const float* x  = (const float*)d_in[0];
  const int*   ei = (const int*)d_in[1];
  const float* W1 = (const float*)d_in[2];
  const float* b1 = (const float*)d_in[3];
  const float* W2 = (const float*)d_in[4];
  const float* b2 = (const float*)d_in[5];
  float* out = (float*)d_out;

  const int M = in_sizes[0] / 512;  // 50000
  const int E = in_sizes[1] / 2;    // 800000
  const int qdiv = (M + 3) >> 2;

  auto alignup = [](size_t v) { return (v + 255) & ~(size_t)255; };
  char* p = (char*)d_ws;
  unsigned short* xb  = (unsigned short*)p; p += alignup((size_t)M * 512 * 2);
  unsigned short* h1b = (unsigned short*)p; p += alignup((size_t)M * 512 * 2);  // blocked
  unsigned short* r1b = (unsigned short*)p; p += alignup((size_t)M * 512 * 2);  // blocked
  unsigned short* w1b = (unsigned short*)p; p += alignup(512 * 512 * 2);
  unsigned short* w2b = (unsigned short*)p; p += alignup(512 * 512 * 2);
  float* dis = (float*)p; p += alignup((size_t)M * 4);
  int* ptr4  = (int*)p;   p += alignup(((size_t)M * 4 + 1) * 4);
  int* eidx  = (int*)p;   p += alignup((size_t)E * 4);
  int* flag  = (int*)p;   p += alignup(256);
  int* bsum  = (int*)p;   p += alignup(1024);
  int* cnt4 = (int*)h1b;  // CSR temporaries alias h1b (dead before GEMM1 writes h1b)
  int* cur4 = (int*)((char*)h1b + alignup((size_t)M * 16));
  unsigned short* h2b = xb;  // xb dead after GEMM1 (blocked)

  const int n4 = M * 4;
  hipMemsetAsync(cnt4, 0, (size_t)n4 * 4, stream);
  detect64_kernel<<<1, 64, 0, stream>>>(ei, flag);

  prep_kernel<<<2048, 256, 0, stream>>>((const float4*)x, (ushort4*)xb, M * 128,
                                        W1, w1b, W2, w2b);

  const int B = (n4 + 1023) / 1024;
  count_kernel<<<(E + 255) / 256, 256, 0, stream>>>(ei, flag, cnt4, E, qdiv);
  scan_bsum_kernel<<<B, 1024, 0, stream>>>(cnt4, bsum, n4);
  scan_boff_kernel<<<1, 1024, 0, stream>>>(bsum, ptr4 + n4, B);
  scan_fill_kernel<<<B, 1024, 0, stream>>>(cnt4, bsum, ptr4, cur4, dis, n4);
  fill_kernel<<<(E + 255) / 256, 256, 0, stream>>>(ei, flag, cur4, eidx, E, qdiv);

  const int nwg = ((M + 127) / 128) * 4;
  const int nag = ((M + 31) / 32) * 8;
  gemm_kernel<false, true><<<nwg, 256, 0, stream>>>(xb, w1b, dis, h1b, M);
  agg_kernel<false><<<nag, 256, 0, stream>>>(h1b, eidx, ptr4, dis, b1, (void*)r1b, M);
  gemm_kernel<true, true><<<nwg, 256, 0, stream>>>(r1b, w2b, dis, h2b, M);
  agg_kernel<true><<<nag, 256, 0, stream>>>(h2b, eidx, ptr4, dis, b2, (void*)out, M);
}

// Round 18
// 372.094 us; speedup vs baseline: 1.0045x; 1.0045x over previous
//
#include <hip/hip_runtime.h>
#include <hip/hip_bf16.h>

typedef short short8 __attribute__((ext_vector_type(8)));
typedef unsigned short u16x8 __attribute__((ext_vector_type(8)));
typedef float f32x4 __attribute__((ext_vector_type(4)));

#define AS1 __attribute__((address_space(1)))
#define AS3 __attribute__((address_space(3)))

__device__ __forceinline__ void gload16(const void* g, void* l) {
  __builtin_amdgcn_global_load_lds((AS1 void*)g, (AS3 void*)l, 16, 0, 0);
}

__device__ __forceinline__ unsigned short f2bf(float f) {
  unsigned u = __float_as_uint(f);
  u = (u + 0x7FFF + ((u >> 16) & 1)) >> 16;  // RNE
  return (unsigned short)u;
}
__device__ __forceinline__ float bf2f(unsigned short u) {
  return __uint_as_float(((unsigned)u) << 16);
}

// ---------------- prep: x f32->bf16 (vectorized) + W1/W2 transpose-convert ----------------
__global__ void prep_kernel(const float4* __restrict__ x4, ushort4* __restrict__ xb4, int n4,
                            const float* __restrict__ W1, unsigned short* __restrict__ W1t,
                            const float* __restrict__ W2, unsigned short* __restrict__ W2t) {
  const int nthr = gridDim.x * 256;
  for (int i = blockIdx.x * 256 + threadIdx.x; i < n4; i += nthr) {
    float4 v = x4[i];
    ushort4 o;
    o.x = f2bf(v.x); o.y = f2bf(v.y); o.z = f2bf(v.z); o.w = f2bf(v.w);
    xb4[i] = o;
  }
  for (int idx = blockIdx.x * 256 + threadIdx.x; idx < 512 * 512; idx += nthr) {
    const int k = idx >> 9, n = idx & 511;
    W1t[n * 512 + k] = f2bf(W1[idx]);
    W2t[n * 512 + k] = f2bf(W2[idx]);
  }
}

// ---------------- edge dtype detector (wave-parallel) ----------------
__global__ void detect64_kernel(const int* __restrict__ ei32, int* __restrict__ flag) {
  const int lane = threadIdx.x;
  const int v = ei32[2 * lane + 1];
  const unsigned long long m = __ballot(v != 0);
  if (lane == 0) *flag = (m == 0ull) ? 1 : 0;
}

// ---------------- CSR build (per-node lists quartile-sorted by source) ----------------
__global__ void count_kernel(const int* __restrict__ ei32, const int* __restrict__ flag,
                             int* __restrict__ cnt4, int E, int qdiv) {
  int e = blockIdx.x * 256 + threadIdx.x;
  if (e >= E) return;
  const int is64 = *flag;
  const int r = is64 ? ei32[2 * e] : ei32[e];
  const int c = is64 ? ei32[2 * E + 2 * e] : ei32[E + e];
  int q = r / qdiv; q = q > 3 ? 3 : q;
  atomicAdd(&cnt4[c * 4 + q], 1);
}

__global__ void __launch_bounds__(1024) scan_bsum_kernel(const int* __restrict__ cnt,
                                                         int* __restrict__ bsum, int n) {
  __shared__ int ws[16];
  const int tid = threadIdx.x, lane = tid & 63, wid = tid >> 6;
  const int i = blockIdx.x * 1024 + tid;
  int x = (i < n) ? cnt[i] : 0;
#pragma unroll
  for (int d = 1; d < 64; d <<= 1) x += __shfl_xor(x, d, 64);
  if (lane == 0) ws[wid] = x;
  __syncthreads();
  if (tid == 0) {
    int s = 0;
#pragma unroll
    for (int w = 0; w < 16; ++w) s += ws[w];
    bsum[blockIdx.x] = s;
  }
}

__global__ void __launch_bounds__(1024) scan_boff_kernel(int* __restrict__ bsum,
                                                         int* __restrict__ total, int B) {
  __shared__ int ws[16];
  const int tid = threadIdx.x, lane = tid & 63, wid = tid >> 6;
  const int v = (tid < B) ? bsum[tid] : 0;
  int x = v;
#pragma unroll
  for (int d = 1; d < 64; d <<= 1) {
    int y = __shfl_up(x, d, 64);
    if (lane >= d) x += y;
  }
  if (lane == 63) ws[wid] = x;
  __syncthreads();
  if (tid < 16) {
    int wv = ws[tid];
    int wx = wv;
#pragma unroll
    for (int d = 1; d < 16; d <<= 1) {
      int y = __shfl_up(wx, d, 64);
      if (tid >= d) wx += y;
    }
    ws[tid] = wx - wv;
  }
  __syncthreads();
  const int excl = ws[wid] + (x - v);
  if (tid < B) bsum[tid] = excl;
  if (tid == B - 1) *total = excl + v;
}

__global__ void __launch_bounds__(1024) scan_fill_kernel(const int* __restrict__ cnt,
    const int* __restrict__ boff, int* __restrict__ ptr, int* __restrict__ cur,
    float* __restrict__ dis, int n) {
  __shared__ int ws[16];
  const int tid = threadIdx.x, lane = tid & 63, wid = tid >> 6;
  const int j = blockIdx.x * 1024 + tid;
  const int v = (j < n) ? cnt[j] : 0;
  int x = v;
#pragma unroll
  for (int d = 1; d < 64; d <<= 1) {
    int y = __shfl_up(x, d, 64);
    if (lane >= d) x += y;
  }
  if (lane == 63) ws[wid] = x;
  __syncthreads();
  if (tid < 16) {
    int wv = ws[tid];
    int wx = wv;
#pragma unroll
    for (int d = 1; d < 16; d <<= 1) {
      int y = __shfl_up(wx, d, 64);
      if (tid >= d) wx += y;
    }
    ws[tid] = wx - wv;
  }
  __syncthreads();
  const int v1 = __shfl_down(v, 1, 64);
  const int v2 = __shfl_down(v, 2, 64);
  const int v3 = __shfl_down(v, 3, 64);
  if (j < n) {
    const int excl = boff[blockIdx.x] + ws[wid] + (x - v);
    ptr[j] = excl;
    cur[j] = excl;
    if ((j & 3) == 0) dis[j >> 2] = rsqrtf((float)(v + v1 + v2 + v3 + 1));  // +1 self-loop
  }
}

__global__ void fill_kernel(const int* __restrict__ ei32, const int* __restrict__ flag,
                            int* __restrict__ cur4, int* __restrict__ eidx, int E, int qdiv) {
  int e = blockIdx.x * 256 + threadIdx.x;
  if (e >= E) return;
  const int is64 = *flag;
  const int r = is64 ? ei32[2 * e] : ei32[e];
  const int c = is64 ? ei32[2 * E + 2 * e] : ei32[E + e];
  int q = r / qdiv; q = q > 3 ? 3 : q;
  const int pos = atomicAdd(&cur4[c * 4 + q], 1);
  eidx[pos] = r;
}

// ---------------- bf16 MFMA GEMM: C = (A @ Bt^T) * dscale[row] (R12 form) ----------------
// 128x128 tile, BK=64, single-buffered (32KB LDS, 3+ blocks/CU), XOR slot-swizzle,
// XCD-chunk swizzle. BA: A column-blocked [8][M][64]; BC: C written column-blocked.
template <bool BA, bool BC>
__global__ void __launch_bounds__(256, 3) gemm_kernel(const unsigned short* __restrict__ A,
                                                      const unsigned short* __restrict__ Bt,
                                                      const float* __restrict__ dscale,
                                                      unsigned short* __restrict__ C, int M) {
  __shared__ alignas(128) unsigned short As[8192];
  __shared__ alignas(128) unsigned short Bs[8192];
  const int tid = threadIdx.x;
  const int wave = tid >> 6, lane = tid & 63;
  const int wm = wave >> 1, wn = wave & 1;

  const int nbm = (M + 127) >> 7;
  const int nwg = nbm * 4;
  const int orig = blockIdx.x;
  const int xcd = orig & 7;
  const int q8 = nwg >> 3, r8 = nwg & 7;
  const int wg = (xcd < r8 ? xcd * (q8 + 1) : r8 * (q8 + 1) + (xcd - r8) * q8) + (orig >> 3);
  const int bn = wg & 3;
  const int bm = wg >> 2;

  const int lr = lane >> 3, ls = lane & 7;
  const int fr = lane & 15, ks = lane >> 4;

  f32x4 acc[4][4] = {};

#define STAGE(KO)                                                                          \
  {                                                                                        \
    _Pragma("unroll") for (int i = 0; i < 4; ++i) {                                        \
      int ra = bm * 128 + i * 32 + wave * 8 + lr;                                          \
      ra = ra < M ? ra : M - 1;                                                            \
      const size_t aoff = BA ? ((size_t)(KO)*M + (size_t)ra * 64 + ((ls ^ (lr & 7)) << 3)) \
                             : ((size_t)ra * 512 + (KO) + ((ls ^ (lr & 7)) << 3));         \
      gload16(A + aoff, &As[(i * 32 + wave * 8) * 64]);                                    \
      const int rb = bn * 128 + i * 32 + wave * 8 + lr;                                    \
      gload16(Bt + (size_t)rb * 512 + (KO) + ((ls ^ (lr & 7)) << 3),                       \
              &Bs[(i * 32 + wave * 8) * 64]);                                              \
    }                                                                                      \
  }

  for (int kt = 0; kt < 8; ++kt) {
    if (kt) __syncthreads();
    STAGE(kt * 64)
    __syncthreads();

#pragma unroll
    for (int kk = 0; kk < 2; ++kk) {
      short8 af[4], bfg[4];
#pragma unroll
      for (int m = 0; m < 4; ++m) {
        const int tr = wm * 64 + m * 16 + fr;
        af[m] = *(const short8*)&As[tr * 64 + ((ks * 8 + kk * 32) ^ ((tr & 7) << 3))];
      }
#pragma unroll
      for (int n = 0; n < 4; ++n) {
        const int tb = wn * 64 + n * 16 + fr;
        bfg[n] = *(const short8*)&Bs[tb * 64 + ((ks * 8 + kk * 32) ^ ((tb & 7) << 3))];
      }
#pragma unroll
      for (int m = 0; m < 4; ++m)
#pragma unroll
        for (int n = 0; n < 4; ++n)
          acc[m][n] = __builtin_amdgcn_mfma_f32_16x16x32_bf16(af[m], bfg[n], acc[m][n], 0, 0, 0);
    }
  }
#undef STAGE

  const int rbase = bm * 128 + wm * 64 + (lane >> 4) * 4;
  const int cbase = bn * 128 + wn * 64 + (lane & 15);
  const size_t hseg = (size_t)M * 64;
#pragma unroll
  for (int m = 0; m < 4; ++m)
#pragma unroll
    for (int j = 0; j < 4; ++j) {
      const int r = rbase + m * 16 + j;
      if (r < M) {
        const float ds = dscale[r];
#pragma unroll
        for (int n = 0; n < 4; ++n) {
          const unsigned short val = f2bf(acc[m][n][j] * ds);
          if (BC) {
            const int col = cbase + n * 16;
            C[(size_t)(col >> 6) * hseg + (size_t)r * 64 + (col & 63)] = val;
          } else {
            C[(size_t)r * 512 + cbase + n * 16] = val;
          }
        }
      }
    }
}

// ---------------- aggregation: XCD-pinned slices, software-pipelined gathers (R16) ------
// h layout: [8 slices][M][64]; 8-lane group owns one node. Aligned int4 index loads,
// 4 gathers in flight, next quad's indices prefetched under the gathers. Self-loop and
// bias loads hoisted before the edge loop so their latency hides under it.
template <bool FINAL>
__global__ void __launch_bounds__(256) agg_kernel(const unsigned short* __restrict__ h,
    const int* __restrict__ eidx, const int* __restrict__ ptr4, const float* __restrict__ dis,
    const float* __restrict__ bias, void* __restrict__ outv, int n) {
  const int tid = threadIdx.x;
  const int lane = tid & 63;
  const int slice = blockIdx.x & 7;
  const int g = lane >> 3;
  const int c = lane & 7;
  const int node = (int)(blockIdx.x >> 3) * 32 + (tid >> 6) * 8 + g;
  if (node >= n) return;

  const unsigned short* hs = h + (size_t)slice * ((size_t)n * 64);
  const int coff = c * 8;
  const int fcol = slice * 64 + coff;

#define GATH(S) (*(const u16x8*)(hs + (size_t)(unsigned)(S) * 64 + coff))
#define FMA1(V)                                        \
  _Pragma("unroll") for (int j = 0; j < 8; ++j) acc[j] += bf2f((V)[j]);

  // hoisted independent loads: self-loop row, dis, bias — fly under the edge loop
  const u16x8 vself = GATH(node);
  const float di = dis[node];
  float b[8];
  *(float4*)&b[0] = *(const float4*)(bias + fcol);
  *(float4*)&b[4] = *(const float4*)(bias + fcol + 4);

  const int start = ptr4[node * 4], end = ptr4[node * 4 + 4];
  float acc[8] = {0, 0, 0, 0, 0, 0, 0, 0};

  int e = start;
  const int alim = min(end, (start + 3) & ~3);  // align to 4 for int4 eidx loads
  for (; e < alim; ++e) {
    const u16x8 v = GATH(eidx[e]);
    FMA1(v)
  }
  int4 si;
  if (e + 4 <= end) si = *(const int4*)&eidx[e];
  for (; e + 8 <= end; e += 4) {
    const u16x8 v0 = GATH(si.x), v1 = GATH(si.y), v2 = GATH(si.z), v3 = GATH(si.w);
    si = *(const int4*)&eidx[e + 4];  // next quad's indices fly under the gathers
#pragma unroll
    for (int j = 0; j < 8; ++j)
      acc[j] += bf2f(v0[j]) + bf2f(v1[j]) + bf2f(v2[j]) + bf2f(v3[j]);
  }
  if (e + 4 <= end) {  // last full quad (si already loaded)
    const u16x8 v0 = GATH(si.x), v1 = GATH(si.y), v2 = GATH(si.z), v3 = GATH(si.w);
#pragma unroll
    for (int j = 0; j < 8; ++j)
      acc[j] += bf2f(v0[j]) + bf2f(v1[j]) + bf2f(v2[j]) + bf2f(v3[j]);
    e += 4;
  }
  for (; e < end; ++e) {
    const u16x8 v = GATH(eidx[e]);
    FMA1(v)
  }
  FMA1(vself)  // self loop (loaded up top)
#undef FMA1
#undef GATH

  if (FINAL) {
    float* out = (float*)outv;
    float4 o0, o1;
    o0.x = acc[0] * di + b[0]; o0.y = acc[1] * di + b[1];
    o0.z = acc[2] * di + b[2]; o0.w = acc[3] * di + b[3];
    o1.x = acc[4] * di + b[4]; o1.y = acc[5] * di + b[5];
    o1.z = acc[6] * di + b[6]; o1.w = acc[7] * di + b[7];
    *(float4*)(out + (size_t)node * 512 + fcol) = o0;
    *(float4*)(out + (size_t)node * 512 + fcol + 4) = o1;
  } else {  // column-blocked bf16 (feeds GEMM2 blocked-A)
    unsigned short* out = (unsigned short*)outv;
    u16x8 o;
#pragma unroll
    for (int j = 0; j < 8; ++j) {
      const float t = acc[j] * di + b[j];
      o[j] = f2bf(t > 0.0f ? t : 0.0f);
    }
    *(u16x8*)(out + (size_t)slice * ((size_t)n * 64) + (size_t)node * 64 + coff) = o;
  }
}

// ---------------- launch ----------------
extern "C" void kernel_launch(void* const* d_in, const int* in_sizes, int n_in,
                              void* d_out, int out_size, void* d_ws, size_t ws_size,
                              hipStream_t stream) {
  const float* x  = (const float*)d_in[0];
  const int*   ei = (const int*)d_in[1];
  const float* W1 = (const float*)d_in[2];
  const float* b1 = (const float*)d_in[3];
  const float* W2 = (const float*)d_in[4];
  const float* b2 = (const float*)d_in[5];
  float* out = (float*)d_out;

  const int M = in_sizes[0] / 512;  // 50000
  const int E = in_sizes[1] / 2;    // 800000
  const int qdiv = (M + 3) >> 2;

  auto alignup = [](size_t v) { return (v + 255) & ~(size_t)255; };
  char* p = (char*)d_ws;
  unsigned short* xb  = (unsigned short*)p; p += alignup((size_t)M * 512 * 2);
  unsigned short* h1b = (unsigned short*)p; p += alignup((size_t)M * 512 * 2);  // blocked
  unsigned short* r1b = (unsigned short*)p; p += alignup((size_t)M * 512 * 2);  // blocked
  unsigned short* w1b = (unsigned short*)p; p += alignup(512 * 512 * 2);
  unsigned short* w2b = (unsigned short*)p; p += alignup(512 * 512 * 2);
  float* dis = (float*)p; p += alignup((size_t)M * 4);
  int* ptr4  = (int*)p;   p += alignup(((size_t)M * 4 + 1) * 4);
  int* eidx  = (int*)p;   p += alignup((size_t)E * 4);
  int* flag  = (int*)p;   p += alignup(256);
  int* bsum  = (int*)p;   p += alignup(1024);
  int* cnt4 = (int*)h1b;  // CSR temporaries alias h1b (dead before GEMM1 writes h1b)
  int* cur4 = (int*)((char*)h1b + alignup((size_t)M * 16));
  unsigned short* h2b = xb;  // xb dead after GEMM1 (blocked)

  const int n4 = M * 4;
  hipMemsetAsync(cnt4, 0, (size_t)n4 * 4, stream);
  detect64_kernel<<<1, 64, 0, stream>>>(ei, flag);

  prep_kernel<<<2048, 256, 0, stream>>>((const float4*)x, (ushort4*)xb, M * 128,
                                        W1, w1b, W2, w2b);

  const int B = (n4 + 1023) / 1024;
  count_kernel<<<(E + 255) / 256, 256, 0, stream>>>(ei, flag, cnt4, E, qdiv);
  scan_bsum_kernel<<<B, 1024, 0, stream>>>(cnt4, bsum, n4);
  scan_boff_kernel<<<1, 1024, 0, stream>>>(bsum, ptr4 + n4, B);
  scan_fill_kernel<<<B, 1024, 0, stream>>>(cnt4, bsum, ptr4, cur4, dis, n4);
  fill_kernel<<<(E + 255) / 256, 256, 0, stream>>>(ei, flag, cur4, eidx, E, qdiv);

  const int nwg = ((M + 127) / 128) * 4;
  const int nag = ((M + 31) / 32) * 8;
  gemm_kernel<false, true><<<nwg, 256, 0, stream>>>(xb, w1b, dis, h1b, M);
  agg_kernel<false><<<nag, 256, 0, stream>>>(h1b, eidx, ptr4, dis, b1, (void*)r1b, M);
  gemm_kernel<true, true><<<nwg, 256, 0, stream>>>(r1b, w2b, dis, h2b, M);
  agg_kernel<true><<<nag, 256, 0, stream>>>(h2b, eidx, ptr4, dis, b2, (void*)out, M);
}

// Round 19
// 370.381 us; speedup vs baseline: 1.0091x; 1.0046x over previous
//
#include <hip/hip_runtime.h>
#include <hip/hip_bf16.h>

typedef short short8 __attribute__((ext_vector_type(8)));
typedef unsigned short u16x8 __attribute__((ext_vector_type(8)));
typedef float f32x4 __attribute__((ext_vector_type(4)));

#define AS1 __attribute__((address_space(1)))
#define AS3 __attribute__((address_space(3)))

__device__ __forceinline__ void gload16(const void* g, void* l) {
  __builtin_amdgcn_global_load_lds((AS1 void*)g, (AS3 void*)l, 16, 0, 0);
}

__device__ __forceinline__ unsigned short f2bf(float f) {
  unsigned u = __float_as_uint(f);
  u = (u + 0x7FFF + ((u >> 16) & 1)) >> 16;  // RNE
  return (unsigned short)u;
}
__device__ __forceinline__ float bf2f(unsigned short u) {
  return __uint_as_float(((unsigned)u) << 16);
}

// ---------------- prep: x f32->bf16 (vectorized) + W1/W2 transpose-convert ----------------
__global__ void prep_kernel(const float4* __restrict__ x4, ushort4* __restrict__ xb4, int n4,
                            const float* __restrict__ W1, unsigned short* __restrict__ W1t,
                            const float* __restrict__ W2, unsigned short* __restrict__ W2t) {
  const int nthr = gridDim.x * 256;
  for (int i = blockIdx.x * 256 + threadIdx.x; i < n4; i += nthr) {
    float4 v = x4[i];
    ushort4 o;
    o.x = f2bf(v.x); o.y = f2bf(v.y); o.z = f2bf(v.z); o.w = f2bf(v.w);
    xb4[i] = o;
  }
  for (int idx = blockIdx.x * 256 + threadIdx.x; idx < 512 * 512; idx += nthr) {
    const int k = idx >> 9, n = idx & 511;
    W1t[n * 512 + k] = f2bf(W1[idx]);
    W2t[n * 512 + k] = f2bf(W2[idx]);
  }
}

// ---------------- edge dtype detector (wave-parallel) ----------------
__global__ void detect64_kernel(const int* __restrict__ ei32, int* __restrict__ flag) {
  const int lane = threadIdx.x;
  const int v = ei32[2 * lane + 1];
  const unsigned long long m = __ballot(v != 0);
  if (lane == 0) *flag = (m == 0ull) ? 1 : 0;
}

// ---------------- CSR build (per-node lists quartile-sorted by source) ----------------
__global__ void count_kernel(const int* __restrict__ ei32, const int* __restrict__ flag,
                             int* __restrict__ cnt4, int E, int qdiv) {
  int e = blockIdx.x * 256 + threadIdx.x;
  if (e >= E) return;
  const int is64 = *flag;
  const int r = is64 ? ei32[2 * e] : ei32[e];
  const int c = is64 ? ei32[2 * E + 2 * e] : ei32[E + e];
  int q = r / qdiv; q = q > 3 ? 3 : q;
  atomicAdd(&cnt4[c * 4 + q], 1);
}

__global__ void __launch_bounds__(1024) scan_bsum_kernel(const int* __restrict__ cnt,
                                                         int* __restrict__ bsum, int n) {
  __shared__ int ws[16];
  const int tid = threadIdx.x, lane = tid & 63, wid = tid >> 6;
  const int i = blockIdx.x * 1024 + tid;
  int x = (i < n) ? cnt[i] : 0;
#pragma unroll
  for (int d = 1; d < 64; d <<= 1) x += __shfl_xor(x, d, 64);
  if (lane == 0) ws[wid] = x;
  __syncthreads();
  if (tid == 0) {
    int s = 0;
#pragma unroll
    for (int w = 0; w < 16; ++w) s += ws[w];
    bsum[blockIdx.x] = s;
  }
}

__global__ void __launch_bounds__(1024) scan_boff_kernel(int* __restrict__ bsum,
                                                         int* __restrict__ total, int B) {
  __shared__ int ws[16];
  const int tid = threadIdx.x, lane = tid & 63, wid = tid >> 6;
  const int v = (tid < B) ? bsum[tid] : 0;
  int x = v;
#pragma unroll
  for (int d = 1; d < 64; d <<= 1) {
    int y = __shfl_up(x, d, 64);
    if (lane >= d) x += y;
  }
  if (lane == 63) ws[wid] = x;
  __syncthreads();
  if (tid < 16) {
    int wv = ws[tid];
    int wx = wv;
#pragma unroll
    for (int d = 1; d < 16; d <<= 1) {
      int y = __shfl_up(wx, d, 64);
      if (tid >= d) wx += y;
    }
    ws[tid] = wx - wv;
  }
  __syncthreads();
  const int excl = ws[wid] + (x - v);
  if (tid < B) bsum[tid] = excl;
  if (tid == B - 1) *total = excl + v;
}

__global__ void __launch_bounds__(1024) scan_fill_kernel(const int* __restrict__ cnt,
    const int* __restrict__ boff, int* __restrict__ ptr, int* __restrict__ cur,
    float* __restrict__ dis, int n) {
  __shared__ int ws[16];
  const int tid = threadIdx.x, lane = tid & 63, wid = tid >> 6;
  const int j = blockIdx.x * 1024 + tid;
  const int v = (j < n) ? cnt[j] : 0;
  int x = v;
#pragma unroll
  for (int d = 1; d < 64; d <<= 1) {
    int y = __shfl_up(x, d, 64);
    if (lane >= d) x += y;
  }
  if (lane == 63) ws[wid] = x;
  __syncthreads();
  if (tid < 16) {
    int wv = ws[tid];
    int wx = wv;
#pragma unroll
    for (int d = 1; d < 16; d <<= 1) {
      int y = __shfl_up(wx, d, 64);
      if (tid >= d) wx += y;
    }
    ws[tid] = wx - wv;
  }
  __syncthreads();
  const int v1 = __shfl_down(v, 1, 64);
  const int v2 = __shfl_down(v, 2, 64);
  const int v3 = __shfl_down(v, 3, 64);
  if (j < n) {
    const int excl = boff[blockIdx.x] + ws[wid] + (x - v);
    ptr[j] = excl;
    cur[j] = excl;
    if ((j & 3) == 0) dis[j >> 2] = rsqrtf((float)(v + v1 + v2 + v3 + 1));  // +1 self-loop
  }
}

// eidx stored as ushort (M=50000 < 65536): halves the index stream
__global__ void fill_kernel(const int* __restrict__ ei32, const int* __restrict__ flag,
                            int* __restrict__ cur4, unsigned short* __restrict__ eidx16,
                            int E, int qdiv) {
  int e = blockIdx.x * 256 + threadIdx.x;
  if (e >= E) return;
  const int is64 = *flag;
  const int r = is64 ? ei32[2 * e] : ei32[e];
  const int c = is64 ? ei32[2 * E + 2 * e] : ei32[E + e];
  int q = r / qdiv; q = q > 3 ? 3 : q;
  const int pos = atomicAdd(&cur4[c * 4 + q], 1);
  eidx16[pos] = (unsigned short)r;
}

// ---------------- bf16 MFMA GEMM: C = (A @ Bt^T) * dscale[row] ----------------
// 128x128 tile, BK=64, DOUBLE-buffered with COUNTED vmcnt (T4): next tile's 8 loads/thread
// stay in flight across raw s_barrier (vmcnt(8) waits only the current buffer's 8 oldest).
// This is the m218 counted-vs-drain0 lever; R3's failure was __syncthreads' forced vmcnt(0)
// draining the prefetch. XOR slot-swizzle, XCD-chunk swizzle.
// BA: A column-blocked [8][M][64]; BC: C written column-blocked.
template <bool BA, bool BC>
__global__ void __launch_bounds__(256, 2) gemm_kernel(const unsigned short* __restrict__ A,
                                                      const unsigned short* __restrict__ Bt,
                                                      const float* __restrict__ dscale,
                                                      unsigned short* __restrict__ C, int M) {
  __shared__ alignas(128) unsigned short As[2][8192];
  __shared__ alignas(128) unsigned short Bs[2][8192];
  const int tid = threadIdx.x;
  const int wave = tid >> 6, lane = tid & 63;
  const int wm = wave >> 1, wn = wave & 1;

  const int nbm = (M + 127) >> 7;
  const int nwg = nbm * 4;
  const int orig = blockIdx.x;
  const int xcd = orig & 7;
  const int q8 = nwg >> 3, r8 = nwg & 7;
  const int wg = (xcd < r8 ? xcd * (q8 + 1) : r8 * (q8 + 1) + (xcd - r8) * q8) + (orig >> 3);
  const int bn = wg & 3;
  const int bm = wg >> 2;

  const int lr = lane >> 3, ls = lane & 7;
  const int fr = lane & 15, ks = lane >> 4;

  f32x4 acc[4][4] = {};

  // 8 gload16 per thread per STAGE (4 iters x A,B)
#define STAGE(BUF, KO)                                                                     \
  {                                                                                        \
    _Pragma("unroll") for (int i = 0; i < 4; ++i) {                                        \
      int ra = bm * 128 + i * 32 + wave * 8 + lr;                                          \
      ra = ra < M ? ra : M - 1;                                                            \
      const size_t aoff = BA ? ((size_t)(KO)*M + (size_t)ra * 64 + ((ls ^ (lr & 7)) << 3)) \
                             : ((size_t)ra * 512 + (KO) + ((ls ^ (lr & 7)) << 3));         \
      gload16(A + aoff, &As[BUF][(i * 32 + wave * 8) * 64]);                               \
      const int rb = bn * 128 + i * 32 + wave * 8 + lr;                                    \
      gload16(Bt + (size_t)rb * 512 + (KO) + ((ls ^ (lr & 7)) << 3),                       \
              &Bs[BUF][(i * 32 + wave * 8) * 64]);                                         \
    }                                                                                      \
  }

  STAGE(0, 0)

  int buf = 0;
  for (int kt = 0; kt < 8; ++kt) {
    if (kt < 7) {
      STAGE(buf ^ 1, (kt + 1) * 64)
      // wait only the CURRENT buffer's 8 oldest loads; prefetch (8 newer) stays in flight
      asm volatile("s_waitcnt vmcnt(8)" ::: "memory");
    } else {
      asm volatile("s_waitcnt vmcnt(0)" ::: "memory");
    }
    __builtin_amdgcn_s_barrier();       // all waves: current buf fully in LDS
    asm volatile("" ::: "memory");

#pragma unroll
    for (int kk = 0; kk < 2; ++kk) {
      short8 af[4], bfg[4];
#pragma unroll
      for (int m = 0; m < 4; ++m) {
        const int tr = wm * 64 + m * 16 + fr;
        af[m] = *(const short8*)&As[buf][tr * 64 + ((ks * 8 + kk * 32) ^ ((tr & 7) << 3))];
      }
#pragma unroll
      for (int n = 0; n < 4; ++n) {
        const int tb = wn * 64 + n * 16 + fr;
        bfg[n] = *(const short8*)&Bs[buf][tb * 64 + ((ks * 8 + kk * 32) ^ ((tb & 7) << 3))];
      }
#pragma unroll
      for (int m = 0; m < 4; ++m)
#pragma unroll
        for (int n = 0; n < 4; ++n)
          acc[m][n] = __builtin_amdgcn_mfma_f32_16x16x32_bf16(af[m], bfg[n], acc[m][n], 0, 0, 0);
    }

    asm volatile("" ::: "memory");
    __builtin_amdgcn_s_barrier();       // all waves done reading buf before it's re-staged
    buf ^= 1;
  }
#undef STAGE

  const int rbase = bm * 128 + wm * 64 + (lane >> 4) * 4;
  const int cbase = bn * 128 + wn * 64 + (lane & 15);
  const size_t hseg = (size_t)M * 64;
#pragma unroll
  for (int m = 0; m < 4; ++m)
#pragma unroll
    for (int j = 0; j < 4; ++j) {
      const int r = rbase + m * 16 + j;
      if (r < M) {
        const float ds = dscale[r];
#pragma unroll
        for (int n = 0; n < 4; ++n) {
          const unsigned short val = f2bf(acc[m][n][j] * ds);
          if (BC) {
            const int col = cbase + n * 16;
            C[(size_t)(col >> 6) * hseg + (size_t)r * 64 + (col & 63)] = val;
          } else {
            C[(size_t)r * 512 + cbase + n * 16] = val;
          }
        }
      }
    }
}

// ---------------- aggregation: XCD-pinned slices, software-pipelined gathers (R16) ------
// h layout: [8 slices][M][64]; 8-lane group owns one node. Aligned ushort4 index loads,
// 4 gathers in flight, next quad's indices prefetched under the gathers.
template <bool FINAL>
__global__ void __launch_bounds__(256) agg_kernel(const unsigned short* __restrict__ h,
    const unsigned short* __restrict__ eidx16, const int* __restrict__ ptr4,
    const float* __restrict__ dis, const float* __restrict__ bias, void* __restrict__ outv,
    int n) {
  const int tid = threadIdx.x;
  const int lane = tid & 63;
  const int slice = blockIdx.x & 7;
  const int g = lane >> 3;
  const int c = lane & 7;
  const int node = (int)(blockIdx.x >> 3) * 32 + (tid >> 6) * 8 + g;
  if (node >= n) return;

  const unsigned short* hs = h + (size_t)slice * ((size_t)n * 64);
  const int coff = c * 8;

  const int start = ptr4[node * 4], end = ptr4[node * 4 + 4];
  float acc[8] = {0, 0, 0, 0, 0, 0, 0, 0};

#define GATH(S) (*(const u16x8*)(hs + (size_t)(unsigned)(S) * 64 + coff))
#define FMA1(V)                                        \
  _Pragma("unroll") for (int j = 0; j < 8; ++j) acc[j] += bf2f((V)[j]);

  int e = start;
  const int alim = min(end, (start + 3) & ~3);  // align to 4 for ushort4 loads
  for (; e < alim; ++e) {
    const u16x8 v = GATH(eidx16[e]);
    FMA1(v)
  }
  ushort4 si;
  if (e + 4 <= end) si = *(const ushort4*)&eidx16[e];
  for (; e + 8 <= end; e += 4) {
    const u16x8 v0 = GATH(si.x), v1 = GATH(si.y), v2 = GATH(si.z), v3 = GATH(si.w);
    si = *(const ushort4*)&eidx16[e + 4];  // next quad's indices fly under the gathers
#pragma unroll
    for (int j = 0; j < 8; ++j)
      acc[j] += bf2f(v0[j]) + bf2f(v1[j]) + bf2f(v2[j]) + bf2f(v3[j]);
  }
  if (e + 4 <= end) {  // last full quad (si already loaded)
    const u16x8 v0 = GATH(si.x), v1 = GATH(si.y), v2 = GATH(si.z), v3 = GATH(si.w);
#pragma unroll
    for (int j = 0; j < 8; ++j)
      acc[j] += bf2f(v0[j]) + bf2f(v1[j]) + bf2f(v2[j]) + bf2f(v3[j]);
    e += 4;
  }
  for (; e < end; ++e) {
    const u16x8 v = GATH(eidx16[e]);
    FMA1(v)
  }
  {  // self loop
    const u16x8 v = GATH(node);
    FMA1(v)
  }
#undef FMA1
#undef GATH

  const float di = dis[node];
  const int fcol = slice * 64 + coff;
  float b[8];
  *(float4*)&b[0] = *(const float4*)(bias + fcol);
  *(float4*)&b[4] = *(const float4*)(bias + fcol + 4);

  if (FINAL) {
    float* out = (float*)outv;
    float4 o0, o1;
    o0.x = acc[0] * di + b[0]; o0.y = acc[1] * di + b[1];
    o0.z = acc[2] * di + b[2]; o0.w = acc[3] * di + b[3];
    o1.x = acc[4] * di + b[4]; o1.y = acc[5] * di + b[5];
    o1.z = acc[6] * di + b[6]; o1.w = acc[7] * di + b[7];
    *(float4*)(out + (size_t)node * 512 + fcol) = o0;
    *(float4*)(out + (size_t)node * 512 + fcol + 4) = o1;
  } else {  // column-blocked bf16 (feeds GEMM2 blocked-A)
    unsigned short* out = (unsigned short*)outv;
    u16x8 o;
#pragma unroll
    for (int j = 0; j < 8; ++j) {
      const float t = acc[j] * di + b[j];
      o[j] = f2bf(t > 0.0f ? t : 0.0f);
    }
    *(u16x8*)(out + (size_t)slice * ((size_t)n * 64) + (size_t)node * 64 + coff) = o;
  }
}

// ---------------- launch ----------------
extern "C" void kernel_launch(void* const* d_in, const int* in_sizes, int n_in,
                              void* d_out, int out_size, void* d_ws, size_t ws_size,
                              hipStream_t stream) {
  const float* x  = (const float*)d_in[0];
  const int*   ei = (const int*)d_in[1];
  const float* W1 = (const float*)d_in[2];
  const float* b1 = (const float*)d_in[3];
  const float* W2 = (const float*)d_in[4];
  const float* b2 = (const float*)d_in[5];
  float* out = (float*)d_out;

  const int M = in_sizes[0] / 512;  // 50000
  const int E = in_sizes[1] / 2;    // 800000
  const int qdiv = (M + 3) >> 2;

  auto alignup = [](size_t v) { return (v + 255) & ~(size_t)255; };
  char* p = (char*)d_ws;
  unsigned short* xb  = (unsigned short*)p; p += alignup((size_t)M * 512 * 2);
  unsigned short* h1b = (unsigned short*)p; p += alignup((size_t)M * 512 * 2);  // blocked
  unsigned short* r1b = (unsigned short*)p; p += alignup((size_t)M * 512 * 2);  // blocked
  unsigned short* w1b = (unsigned short*)p; p += alignup(512 * 512 * 2);
  unsigned short* w2b = (unsigned short*)p; p += alignup(512 * 512 * 2);
  float* dis = (float*)p; p += alignup((size_t)M * 4);
  int* ptr4  = (int*)p;   p += alignup(((size_t)M * 4 + 1) * 4);
  unsigned short* eidx16 = (unsigned short*)p; p += alignup((size_t)E * 2);
  int* flag  = (int*)p;   p += alignup(256);
  int* bsum  = (int*)p;   p += alignup(1024);
  int* cnt4 = (int*)h1b;  // CSR temporaries alias h1b (dead before GEMM1 writes h1b)
  int* cur4 = (int*)((char*)h1b + alignup((size_t)M * 16));
  unsigned short* h2b = xb;  // xb dead after GEMM1 (blocked)

  const int n4 = M * 4;
  hipMemsetAsync(cnt4, 0, (size_t)n4 * 4, stream);
  detect64_kernel<<<1, 64, 0, stream>>>(ei, flag);

  prep_kernel<<<2048, 256, 0, stream>>>((const float4*)x, (ushort4*)xb, M * 128,
                                        W1, w1b, W2, w2b);

  const int B = (n4 + 1023) / 1024;
  count_kernel<<<(E + 255) / 256, 256, 0, stream>>>(ei, flag, cnt4, E, qdiv);
  scan_bsum_kernel<<<B, 1024, 0, stream>>>(cnt4, bsum, n4);
  scan_boff_kernel<<<1, 1024, 0, stream>>>(bsum, ptr4 + n4, B);
  scan_fill_kernel<<<B, 1024, 0, stream>>>(cnt4, bsum, ptr4, cur4, dis, n4);
  fill_kernel<<<(E + 255) / 256, 256, 0, stream>>>(ei, flag, cur4, eidx16, E, qdiv);

  const int nwg = ((M + 127) / 128) * 4;
  const int nag = ((M + 31) / 32) * 8;
  gemm_kernel<false, true><<<nwg, 256, 0, stream>>>(xb, w1b, dis, h1b, M);
  agg_kernel<false><<<nag, 256, 0, stream>>>(h1b, eidx16, ptr4, dis, b1, (void*)r1b, M);
  gemm_kernel<true, true><<<nwg, 256, 0, stream>>>(r1b, w2b, dis, h2b, M);
  agg_kernel<true><<<nag, 256, 0, stream>>>(h2b, eidx16, ptr4, dis, b2, (void*)out, M);
}

// Round 20
// 349.645 us; speedup vs baseline: 1.0690x; 1.0593x over previous
//
#include <hip/hip_runtime.h>
#include <hip/hip_bf16.h>

typedef short short8 __attribute__((ext_vector_type(8)));
typedef unsigned short u16x8 __attribute__((ext_vector_type(8)));
typedef float f32x4 __attribute__((ext_vector_type(4)));

#define AS1 __attribute__((address_space(1)))
#define AS3 __attribute__((address_space(3)))

__device__ __forceinline__ void gload16(const void* g, void* l) {
  __builtin_amdgcn_global_load_lds((AS1 void*)g, (AS3 void*)l, 16, 0, 0);
}

__device__ __forceinline__ unsigned short f2bf(float f) {
  unsigned u = __float_as_uint(f);
  u = (u + 0x7FFF + ((u >> 16) & 1)) >> 16;  // RNE
  return (unsigned short)u;
}
__device__ __forceinline__ float bf2f(unsigned short u) {
  return __uint_as_float(((unsigned)u) << 16);
}

// ---------------- prep: x f32->bf16 (vectorized) + W1/W2 transpose-convert ----------------
__global__ void prep_kernel(const float4* __restrict__ x4, ushort4* __restrict__ xb4, int n4,
                            const float* __restrict__ W1, unsigned short* __restrict__ W1t,
                            const float* __restrict__ W2, unsigned short* __restrict__ W2t) {
  const int nthr = gridDim.x * 256;
  for (int i = blockIdx.x * 256 + threadIdx.x; i < n4; i += nthr) {
    float4 v = x4[i];
    ushort4 o;
    o.x = f2bf(v.x); o.y = f2bf(v.y); o.z = f2bf(v.z); o.w = f2bf(v.w);
    xb4[i] = o;
  }
  for (int idx = blockIdx.x * 256 + threadIdx.x; idx < 512 * 512; idx += nthr) {
    const int k = idx >> 9, n = idx & 511;
    W1t[n * 512 + k] = f2bf(W1[idx]);
    W2t[n * 512 + k] = f2bf(W2[idx]);
  }
}

// ---------------- edge dtype detector (wave-parallel) ----------------
__global__ void detect64_kernel(const int* __restrict__ ei32, int* __restrict__ flag) {
  const int lane = threadIdx.x;
  const int v = ei32[2 * lane + 1];
  const unsigned long long m = __ballot(v != 0);
  if (lane == 0) *flag = (m == 0ull) ? 1 : 0;
}

// ---------------- CSR build (per-node lists quartile-sorted by source) ----------------
__global__ void count_kernel(const int* __restrict__ ei32, const int* __restrict__ flag,
                             int* __restrict__ cnt4, int E, int qdiv) {
  int e = blockIdx.x * 256 + threadIdx.x;
  if (e >= E) return;
  const int is64 = *flag;
  const int r = is64 ? ei32[2 * e] : ei32[e];
  const int c = is64 ? ei32[2 * E + 2 * e] : ei32[E + e];
  int q = r / qdiv; q = q > 3 ? 3 : q;
  atomicAdd(&cnt4[c * 4 + q], 1);
}

__global__ void __launch_bounds__(1024) scan_bsum_kernel(const int* __restrict__ cnt,
                                                         int* __restrict__ bsum, int n) {
  __shared__ int ws[16];
  const int tid = threadIdx.x, lane = tid & 63, wid = tid >> 6;
  const int i = blockIdx.x * 1024 + tid;
  int x = (i < n) ? cnt[i] : 0;
#pragma unroll
  for (int d = 1; d < 64; d <<= 1) x += __shfl_xor(x, d, 64);
  if (lane == 0) ws[wid] = x;
  __syncthreads();
  if (tid == 0) {
    int s = 0;
#pragma unroll
    for (int w = 0; w < 16; ++w) s += ws[w];
    bsum[blockIdx.x] = s;
  }
}

__global__ void __launch_bounds__(1024) scan_boff_kernel(int* __restrict__ bsum,
                                                         int* __restrict__ total, int B) {
  __shared__ int ws[16];
  const int tid = threadIdx.x, lane = tid & 63, wid = tid >> 6;
  const int v = (tid < B) ? bsum[tid] : 0;
  int x = v;
#pragma unroll
  for (int d = 1; d < 64; d <<= 1) {
    int y = __shfl_up(x, d, 64);
    if (lane >= d) x += y;
  }
  if (lane == 63) ws[wid] = x;
  __syncthreads();
  if (tid < 16) {
    int wv = ws[tid];
    int wx = wv;
#pragma unroll
    for (int d = 1; d < 16; d <<= 1) {
      int y = __shfl_up(wx, d, 64);
      if (tid >= d) wx += y;
    }
    ws[tid] = wx - wv;
  }
  __syncthreads();
  const int excl = ws[wid] + (x - v);
  if (tid < B) bsum[tid] = excl;
  if (tid == B - 1) *total = excl + v;
}

__global__ void __launch_bounds__(1024) scan_fill_kernel(const int* __restrict__ cnt,
    const int* __restrict__ boff, int* __restrict__ ptr, int* __restrict__ cur,
    float* __restrict__ dis, int n) {
  __shared__ int ws[16];
  const int tid = threadIdx.x, lane = tid & 63, wid = tid >> 6;
  const int j = blockIdx.x * 1024 + tid;
  const int v = (j < n) ? cnt[j] : 0;
  int x = v;
#pragma unroll
  for (int d = 1; d < 64; d <<= 1) {
    int y = __shfl_up(x, d, 64);
    if (lane >= d) x += y;
  }
  if (lane == 63) ws[wid] = x;
  __syncthreads();
  if (tid < 16) {
    int wv = ws[tid];
    int wx = wv;
#pragma unroll
    for (int d = 1; d < 16; d <<= 1) {
      int y = __shfl_up(wx, d, 64);
      if (tid >= d) wx += y;
    }
    ws[tid] = wx - wv;
  }
  __syncthreads();
  const int v1 = __shfl_down(v, 1, 64);
  const int v2 = __shfl_down(v, 2, 64);
  const int v3 = __shfl_down(v, 3, 64);
  if (j < n) {
    const int excl = boff[blockIdx.x] + ws[wid] + (x - v);
    ptr[j] = excl;
    cur[j] = excl;
    if ((j & 3) == 0) dis[j >> 2] = rsqrtf((float)(v + v1 + v2 + v3 + 1));  // +1 self-loop
  }
}

// eidx stored as ushort (M=50000 < 65536): halves the index stream
__global__ void fill_kernel(const int* __restrict__ ei32, const int* __restrict__ flag,
                            int* __restrict__ cur4, unsigned short* __restrict__ eidx16,
                            int E, int qdiv) {
  int e = blockIdx.x * 256 + threadIdx.x;
  if (e >= E) return;
  const int is64 = *flag;
  const int r = is64 ? ei32[2 * e] : ei32[e];
  const int c = is64 ? ei32[2 * E + 2 * e] : ei32[E + e];
  int q = r / qdiv; q = q > 3 ? 3 : q;
  const int pos = atomicAdd(&cur4[c * 4 + q], 1);
  eidx16[pos] = (unsigned short)r;
}

// ---------------- bf16 MFMA GEMM: C = (A @ Bt^T) * dscale[row] (R12/R16 form) ------------
// 128x128 tile, BK=64, single-buffered (32KB LDS, 3+ blocks/CU — empirically beats all
// double-buffer/persistent variants at this K=512 shape), XOR slot-swizzle, XCD swizzle.
// BA: A column-blocked [8][M][64]; BC: C written column-blocked.
template <bool BA, bool BC>
__global__ void __launch_bounds__(256, 3) gemm_kernel(const unsigned short* __restrict__ A,
                                                      const unsigned short* __restrict__ Bt,
                                                      const float* __restrict__ dscale,
                                                      unsigned short* __restrict__ C, int M) {
  __shared__ alignas(128) unsigned short As[8192];
  __shared__ alignas(128) unsigned short Bs[8192];
  const int tid = threadIdx.x;
  const int wave = tid >> 6, lane = tid & 63;
  const int wm = wave >> 1, wn = wave & 1;

  const int nbm = (M + 127) >> 7;
  const int nwg = nbm * 4;
  const int orig = blockIdx.x;
  const int xcd = orig & 7;
  const int q8 = nwg >> 3, r8 = nwg & 7;
  const int wg = (xcd < r8 ? xcd * (q8 + 1) : r8 * (q8 + 1) + (xcd - r8) * q8) + (orig >> 3);
  const int bn = wg & 3;
  const int bm = wg >> 2;

  const int lr = lane >> 3, ls = lane & 7;
  const int fr = lane & 15, ks = lane >> 4;

  f32x4 acc[4][4] = {};

#define STAGE(KO)                                                                          \
  {                                                                                        \
    _Pragma("unroll") for (int i = 0; i < 4; ++i) {                                        \
      int ra = bm * 128 + i * 32 + wave * 8 + lr;                                          \
      ra = ra < M ? ra : M - 1;                                                            \
      const size_t aoff = BA ? ((size_t)(KO)*M + (size_t)ra * 64 + ((ls ^ (lr & 7)) << 3)) \
                             : ((size_t)ra * 512 + (KO) + ((ls ^ (lr & 7)) << 3));         \
      gload16(A + aoff, &As[(i * 32 + wave * 8) * 64]);                                    \
      const int rb = bn * 128 + i * 32 + wave * 8 + lr;                                    \
      gload16(Bt + (size_t)rb * 512 + (KO) + ((ls ^ (lr & 7)) << 3),                       \
              &Bs[(i * 32 + wave * 8) * 64]);                                              \
    }                                                                                      \
  }

  for (int kt = 0; kt < 8; ++kt) {
    if (kt) __syncthreads();
    STAGE(kt * 64)
    __syncthreads();

#pragma unroll
    for (int kk = 0; kk < 2; ++kk) {
      short8 af[4], bfg[4];
#pragma unroll
      for (int m = 0; m < 4; ++m) {
        const int tr = wm * 64 + m * 16 + fr;
        af[m] = *(const short8*)&As[tr * 64 + ((ks * 8 + kk * 32) ^ ((tr & 7) << 3))];
      }
#pragma unroll
      for (int n = 0; n < 4; ++n) {
        const int tb = wn * 64 + n * 16 + fr;
        bfg[n] = *(const short8*)&Bs[tb * 64 + ((ks * 8 + kk * 32) ^ ((tb & 7) << 3))];
      }
#pragma unroll
      for (int m = 0; m < 4; ++m)
#pragma unroll
        for (int n = 0; n < 4; ++n)
          acc[m][n] = __builtin_amdgcn_mfma_f32_16x16x32_bf16(af[m], bfg[n], acc[m][n], 0, 0, 0);
    }
  }
#undef STAGE

  const int rbase = bm * 128 + wm * 64 + (lane >> 4) * 4;
  const int cbase = bn * 128 + wn * 64 + (lane & 15);
  const size_t hseg = (size_t)M * 64;
#pragma unroll
  for (int m = 0; m < 4; ++m)
#pragma unroll
    for (int j = 0; j < 4; ++j) {
      const int r = rbase + m * 16 + j;
      if (r < M) {
        const float ds = dscale[r];
#pragma unroll
        for (int n = 0; n < 4; ++n) {
          const unsigned short val = f2bf(acc[m][n][j] * ds);
          if (BC) {
            const int col = cbase + n * 16;
            C[(size_t)(col >> 6) * hseg + (size_t)r * 64 + (col & 63)] = val;
          } else {
            C[(size_t)r * 512 + cbase + n * 16] = val;
          }
        }
      }
    }
}

// ---------------- aggregation: XCD-pinned slices, software-pipelined gathers (R19) ------
// h layout: [8 slices][M][64]; 8-lane group owns one node. Aligned ushort4 index loads,
// 4 gathers in flight, next quad's indices prefetched under the gathers.
template <bool FINAL>
__global__ void __launch_bounds__(256) agg_kernel(const unsigned short* __restrict__ h,
    const unsigned short* __restrict__ eidx16, const int* __restrict__ ptr4,
    const float* __restrict__ dis, const float* __restrict__ bias, void* __restrict__ outv,
    int n) {
  const int tid = threadIdx.x;
  const int lane = tid & 63;
  const int slice = blockIdx.x & 7;
  const int g = lane >> 3;
  const int c = lane & 7;
  const int node = (int)(blockIdx.x >> 3) * 32 + (tid >> 6) * 8 + g;
  if (node >= n) return;

  const unsigned short* hs = h + (size_t)slice * ((size_t)n * 64);
  const int coff = c * 8;

  const int start = ptr4[node * 4], end = ptr4[node * 4 + 4];
  float acc[8] = {0, 0, 0, 0, 0, 0, 0, 0};

#define GATH(S) (*(const u16x8*)(hs + (size_t)(unsigned)(S) * 64 + coff))
#define FMA1(V)                                        \
  _Pragma("unroll") for (int j = 0; j < 8; ++j) acc[j] += bf2f((V)[j]);

  int e = start;
  const int alim = min(end, (start + 3) & ~3);  // align to 4 for ushort4 loads
  for (; e < alim; ++e) {
    const u16x8 v = GATH(eidx16[e]);
    FMA1(v)
  }
  ushort4 si;
  if (e + 4 <= end) si = *(const ushort4*)&eidx16[e];
  for (; e + 8 <= end; e += 4) {
    const u16x8 v0 = GATH(si.x), v1 = GATH(si.y), v2 = GATH(si.z), v3 = GATH(si.w);
    si = *(const ushort4*)&eidx16[e + 4];  // next quad's indices fly under the gathers
#pragma unroll
    for (int j = 0; j < 8; ++j)
      acc[j] += bf2f(v0[j]) + bf2f(v1[j]) + bf2f(v2[j]) + bf2f(v3[j]);
  }
  if (e + 4 <= end) {  // last full quad (si already loaded)
    const u16x8 v0 = GATH(si.x), v1 = GATH(si.y), v2 = GATH(si.z), v3 = GATH(si.w);
#pragma unroll
    for (int j = 0; j < 8; ++j)
      acc[j] += bf2f(v0[j]) + bf2f(v1[j]) + bf2f(v2[j]) + bf2f(v3[j]);
    e += 4;
  }
  for (; e < end; ++e) {
    const u16x8 v = GATH(eidx16[e]);
    FMA1(v)
  }
  {  // self loop
    const u16x8 v = GATH(node);
    FMA1(v)
  }
#undef FMA1
#undef GATH

  const float di = dis[node];
  const int fcol = slice * 64 + coff;
  float b[8];
  *(float4*)&b[0] = *(const float4*)(bias + fcol);
  *(float4*)&b[4] = *(const float4*)(bias + fcol + 4);

  if (FINAL) {
    float* out = (float*)outv;
    float4 o0, o1;
    o0.x = acc[0] * di + b[0]; o0.y = acc[1] * di + b[1];
    o0.z = acc[2] * di + b[2]; o0.w = acc[3] * di + b[3];
    o1.x = acc[4] * di + b[4]; o1.y = acc[5] * di + b[5];
    o1.z = acc[6] * di + b[6]; o1.w = acc[7] * di + b[7];
    *(float4*)(out + (size_t)node * 512 + fcol) = o0;
    *(float4*)(out + (size_t)node * 512 + fcol + 4) = o1;
  } else {  // column-blocked bf16 (feeds GEMM2 blocked-A)
    unsigned short* out = (unsigned short*)outv;
    u16x8 o;
#pragma unroll
    for (int j = 0; j < 8; ++j) {
      const float t = acc[j] * di + b[j];
      o[j] = f2bf(t > 0.0f ? t : 0.0f);
    }
    *(u16x8*)(out + (size_t)slice * ((size_t)n * 64) + (size_t)node * 64 + coff) = o;
  }
}

// ---------------- launch ----------------
extern "C" void kernel_launch(void* const* d_in, const int* in_sizes, int n_in,
                              void* d_out, int out_size, void* d_ws, size_t ws_size,
                              hipStream_t stream) {
  const float* x  = (const float*)d_in[0];
  const int*   ei = (const int*)d_in[1];
  const float* W1 = (const float*)d_in[2];
  const float* b1 = (const float*)d_in[3];
  const float* W2 = (const float*)d_in[4];
  const float* b2 = (const float*)d_in[5];
  float* out = (float*)d_out;

  const int M = in_sizes[0] / 512;  // 50000
  const int E = in_sizes[1] / 2;    // 800000
  const int qdiv = (M + 3) >> 2;

  auto alignup = [](size_t v) { return (v + 255) & ~(size_t)255; };
  char* p = (char*)d_ws;
  unsigned short* xb  = (unsigned short*)p; p += alignup((size_t)M * 512 * 2);
  unsigned short* h1b = (unsigned short*)p; p += alignup((size_t)M * 512 * 2);  // blocked
  unsigned short* r1b = (unsigned short*)p; p += alignup((size_t)M * 512 * 2);  // blocked
  unsigned short* w1b = (unsigned short*)p; p += alignup(512 * 512 * 2);
  unsigned short* w2b = (unsigned short*)p; p += alignup(512 * 512 * 2);
  float* dis = (float*)p; p += alignup((size_t)M * 4);
  int* ptr4  = (int*)p;   p += alignup(((size_t)M * 4 + 1) * 4);
  unsigned short* eidx16 = (unsigned short*)p; p += alignup((size_t)E * 2);
  int* flag  = (int*)p;   p += alignup(256);
  int* bsum  = (int*)p;   p += alignup(1024);
  int* cnt4 = (int*)h1b;  // CSR temporaries alias h1b (dead before GEMM1 writes h1b)
  int* cur4 = (int*)((char*)h1b + alignup((size_t)M * 16));
  unsigned short* h2b = xb;  // xb dead after GEMM1 (blocked)

  const int n4 = M * 4;
  hipMemsetAsync(cnt4, 0, (size_t)n4 * 4, stream);
  detect64_kernel<<<1, 64, 0, stream>>>(ei, flag);

  prep_kernel<<<2048, 256, 0, stream>>>((const float4*)x, (ushort4*)xb, M * 128,
                                        W1, w1b, W2, w2b);

  const int B = (n4 + 1023) / 1024;
  count_kernel<<<(E + 255) / 256, 256, 0, stream>>>(ei, flag, cnt4, E, qdiv);
  scan_bsum_kernel<<<B, 1024, 0, stream>>>(cnt4, bsum, n4);
  scan_boff_kernel<<<1, 1024, 0, stream>>>(bsum, ptr4 + n4, B);
  scan_fill_kernel<<<B, 1024, 0, stream>>>(cnt4, bsum, ptr4, cur4, dis, n4);
  fill_kernel<<<(E + 255) / 256, 256, 0, stream>>>(ei, flag, cur4, eidx16, E, qdiv);

  const int nwg = ((M + 127) / 128) * 4;
  const int nag = ((M + 31) / 32) * 8;
  gemm_kernel<false, true><<<nwg, 256, 0, stream>>>(xb, w1b, dis, h1b, M);
  agg_kernel<false><<<nag, 256, 0, stream>>>(h1b, eidx16, ptr4, dis, b1, (void*)r1b, M);
  gemm_kernel<true, true><<<nwg, 256, 0, stream>>>(r1b, w2b, dis, h2b, M);
  agg_kernel<true><<<nag, 256, 0, stream>>>(h2b, eidx16, ptr4, dis, b2, (void*)out, M);
}